// Round 10
// baseline (1236.782 us; speedup 1.0000x reference)
//
#include <hip/hip_runtime.h>
#include <math.h>

constexpr int N_NODES = 40000;
constexpr int N_EDGES = 500000;
constexpr int ETOT    = N_EDGES + N_NODES;
constexpr int IN_DIM  = 128;
constexpr int ED_DIM  = 16;
constexpr int FEAT    = 256;   // H*C for every layer
constexpr int BATCH   = 128;
constexpr float NEG   = 0.2f;
constexpr int NCHUNK  = (N_NODES + 255) / 256;  // 157

typedef __bf16 bf16x8 __attribute__((ext_vector_type(8)));
typedef float  f32x4  __attribute__((ext_vector_type(4)));

// ---------------- CSR build (by dst, incl. self loops) ----------------
__global__ __launch_bounds__(256) void k_deg(const int* __restrict__ dst, int* __restrict__ deg)
{
    int e = blockIdx.x * 256 + threadIdx.x;
    if (e >= ETOT) return;
    int v = e < N_EDGES ? dst[e] : e - N_EDGES;
    atomicAdd(&deg[v], 1);
}

__global__ __launch_bounds__(256) void k_scan1(const int* __restrict__ deg, int* __restrict__ bsum)
{
    __shared__ int s[256];
    int t = threadIdx.x;
    int idx = blockIdx.x * 256 + t;
    s[t] = idx < N_NODES ? deg[idx] : 0;
    __syncthreads();
    for (int st = 128; st; st >>= 1) { if (t < st) s[t] += s[t + st]; __syncthreads(); }
    if (t == 0) bsum[blockIdx.x] = s[0];
}

__global__ __launch_bounds__(256) void k_scan2(const int* __restrict__ bsum,
    int* __restrict__ boff, int* __restrict__ rowptr)
{
    __shared__ int s[256];
    int t = threadIdx.x;
    int v = t < NCHUNK ? bsum[t] : 0;
    s[t] = v;
    __syncthreads();
    for (int off = 1; off < 256; off <<= 1) {
        int x = (t >= off) ? s[t - off] : 0;
        __syncthreads();
        s[t] += x;
        __syncthreads();
    }
    if (t < NCHUNK) boff[t] = s[t] - v;
    if (t == 0) rowptr[N_NODES] = ETOT;
}

__global__ __launch_bounds__(256) void k_scan3(const int* __restrict__ deg,
    const int* __restrict__ boff, int* __restrict__ rowptr)
{
    __shared__ int s[256];
    int t = threadIdx.x;
    int idx = blockIdx.x * 256 + t;
    int v = idx < N_NODES ? deg[idx] : 0;
    s[t] = v;
    __syncthreads();
    for (int off = 1; off < 256; off <<= 1) {
        int x = (t >= off) ? s[t - off] : 0;
        __syncthreads();
        s[t] += x;
        __syncthreads();
    }
    if (idx < N_NODES) rowptr[idx] = boff[blockIdx.x] + s[t] - v;
}

// elist2[pos] = (src, eid)
__global__ __launch_bounds__(256) void k_fill(const int* __restrict__ srcA, const int* __restrict__ dst,
    const int* __restrict__ rowptr, int* __restrict__ fill, int2* __restrict__ elist2)
{
    int e = blockIdx.x * 256 + threadIdx.x;
    if (e >= ETOT) return;
    int v = e < N_EDGES ? dst[e]  : e - N_EDGES;
    int s = e < N_EDGES ? srcA[e] : e - N_EDGES;
    int pos = rowptr[v] + atomicAdd(&fill[v], 1);
    elist2[pos] = make_int2(s, e);
}

// ---------------- self-loop mean edge attr via CSR (no atomics) ----------------
__global__ __launch_bounds__(256) void k_loop_csr(const int2* __restrict__ elist2,
    const int* __restrict__ rowptr, const float* __restrict__ ea, float* __restrict__ loop_attr)
{
    int t = blockIdx.x * 256 + threadIdx.x;
    if (t >= N_NODES * ED_DIM) return;
    int n = t >> 4, d = t & 15;
    int p0 = rowptr[n], p1 = rowptr[n + 1];
    float s = 0.f; int c = 0;
    for (int p = p0; p < p1; ++p) {
        int e = elist2[p].y;
        if (e < N_EDGES) { s += ea[(size_t)e * ED_DIM + d]; ++c; }
    }
    loop_attr[t] = s / (float)(c > 0 ? c : 1);
}

// ---------------- split fp32 -> bf16 hi/lo ----------------
__device__ __forceinline__ void bsplit(float x, unsigned short& h, unsigned short& l)
{
    unsigned u = __float_as_uint(x);
    unsigned r = (u + 0x7FFFu + ((u >> 16) & 1u)) >> 16;
    h = (unsigned short)r;
    float rem = x - __uint_as_float(r << 16);
    unsigned u2 = __float_as_uint(rem);
    l = (unsigned short)((u2 + 0x7FFFu + ((u2 >> 16) & 1u)) >> 16);
}

__global__ __launch_bounds__(256) void k_cvt(const float* __restrict__ X,
    unsigned short* __restrict__ Xh, unsigned short* __restrict__ Xl, int n4)
{
    int i = blockIdx.x * 256 + threadIdx.x;
    if (i >= n4) return;
    float4 v = ((const float4*)X)[i];
    ushort4 h, l;
    bsplit(v.x, h.x, l.x);
    bsplit(v.y, h.y, l.y);
    bsplit(v.z, h.z, l.z);
    bsplit(v.w, h.w, l.w);
    ((ushort4*)Xh)[i] = h;
    ((ushort4*)Xl)[i] = l;
}

// W[K][N] fp32 -> WhT/WlT [N][K] bf16 (transposed for B-fragment b128 reads)
__global__ __launch_bounds__(256) void k_cvtT(const float* __restrict__ W,
    unsigned short* __restrict__ WhT, unsigned short* __restrict__ WlT, int K, int N)
{
    int i = blockIdx.x * 256 + threadIdx.x;
    if (i >= K * N) return;
    int k = i / N, n = i - k * N;
    unsigned short h, l;
    bsplit(W[i], h, l);
    WhT[(size_t)n * K + k] = h;
    WlT[(size_t)n * K + k] = l;
}

// ---------------- split-bf16 MFMA GEMM, LDS-free ----------------
// C = Ah·Bh + Ah·Bl + Al·Bh + bias (+relu). 128x128 block, 4 waves, wave = 64x64.
// Fragments loaded straight from global: lane q*16+lm reads row/col lm, k-quad q
// -> each b128 instruction covers 16 full 64B lines. No LDS, no barriers.
// A frag: lane holds A[m=lm][k=q*8+j]; B frag: B^T[n=lm][k=q*8+j];
// D: col=lm, row=q*4+i  (verified on HW in round 9).
__global__ __launch_bounds__(256) void k_mgemm(
    const unsigned short* __restrict__ Ah, const unsigned short* __restrict__ Al,
    const unsigned short* __restrict__ BhT, const unsigned short* __restrict__ BlT,
    const float* __restrict__ bias, float* __restrict__ C,
    int M, int N, int K, int act)
{
    int t = threadIdx.x;
    int lane = t & 63;
    int w = t >> 6;
    int mh = w >> 1, nh = w & 1;
    int bm = blockIdx.x * 128, bn = blockIdx.y * 128;
    int q = lane >> 4, lm = lane & 15;

    size_t aoff[4], boff[4];
    #pragma unroll
    for (int mt = 0; mt < 4; ++mt) {
        int r = bm + mh * 64 + mt * 16 + lm;
        r = r < M ? r : M - 1;
        aoff[mt] = (size_t)r * K + q * 8;
    }
    #pragma unroll
    for (int nt = 0; nt < 4; ++nt) {
        int c = bn + nh * 64 + nt * 16 + lm;
        boff[nt] = (size_t)c * K + q * 8;
    }

    f32x4 acc[4][4] = {};

    for (int k0 = 0; k0 < K; k0 += 32) {
        bf16x8 fah[4], fal[4], fbh[4], fbl[4];
        #pragma unroll
        for (int i = 0; i < 4; ++i) {
            fah[i] = __builtin_bit_cast(bf16x8, *(const uint4*)(Ah  + aoff[i] + k0));
            fal[i] = __builtin_bit_cast(bf16x8, *(const uint4*)(Al  + aoff[i] + k0));
            fbh[i] = __builtin_bit_cast(bf16x8, *(const uint4*)(BhT + boff[i] + k0));
            fbl[i] = __builtin_bit_cast(bf16x8, *(const uint4*)(BlT + boff[i] + k0));
        }
        #pragma unroll
        for (int mt = 0; mt < 4; ++mt)
            #pragma unroll
            for (int nt = 0; nt < 4; ++nt) {
                acc[mt][nt] = __builtin_amdgcn_mfma_f32_16x16x32_bf16(fah[mt], fbh[nt], acc[mt][nt], 0, 0, 0);
                acc[mt][nt] = __builtin_amdgcn_mfma_f32_16x16x32_bf16(fah[mt], fbl[nt], acc[mt][nt], 0, 0, 0);
                acc[mt][nt] = __builtin_amdgcn_mfma_f32_16x16x32_bf16(fal[mt], fbh[nt], acc[mt][nt], 0, 0, 0);
            }
    }

    #pragma unroll
    for (int nt = 0; nt < 4; ++nt) {
        int col = bn + nh * 64 + nt * 16 + lm;
        float bb = bias[col];
        #pragma unroll
        for (int mt = 0; mt < 4; ++mt) {
            #pragma unroll
            for (int i = 0; i < 4; ++i) {
                int row = bm + mh * 64 + mt * 16 + q * 4 + i;
                if (row < M) {
                    float o = acc[mt][nt][i] + bb;
                    if (act) o = fmaxf(o, 0.f);
                    C[(size_t)row * N + col] = o;
                }
            }
        }
    }
}

static void launch_mgemm(const unsigned short* Ah, const unsigned short* Al,
                         const unsigned short* BhT, const unsigned short* BlT,
                         const float* bias, float* C, int M, int N, int K, int act,
                         hipStream_t stream)
{
    dim3 grid((M + 127) / 128, N / 128);
    k_mgemm<<<grid, 256, 0, stream>>>(Ah, Al, BhT, BlT, bias, C, M, N, K, act);
}

// ---------------- fused GATv2 with fused split-precision output ----------------
// OUTMODE: 1 = write bf16 hi/lo only; 2 = write fp32 h AND bf16 hi/lo.
#define XELOAD(s) do {                                                                \
    int src_ = __builtin_amdgcn_readfirstlane(eS[s].x);                               \
    int e_   = __builtin_amdgcn_readfirstlane(eS[s].y);                               \
    const float4* eb4_ = reinterpret_cast<const float4*>(                             \
        (e_ < N_EDGES) ? ea + (size_t)e_ * ED_DIM                                     \
                       : loop_attr + (size_t)src_ * ED_DIM);                          \
    evS[s][0] = eb4_[0]; evS[s][1] = eb4_[1];                                         \
    evS[s][2] = eb4_[2]; evS[s][3] = eb4_[3];                                         \
    xlvS[s] = *(const float4*)(xl + (size_t)src_ * FEAT + base);                      \
} while (0)

#define COMPUTE(s) do {                                                               \
    float ef0_ = 0.f, ef1_ = 0.f, ef2_ = 0.f, ef3_ = 0.f;                             \
    const float* ed_ = (const float*)evS[s];                                          \
    _Pragma("unroll")                                                                 \
    for (int d_ = 0; d_ < ED_DIM; ++d_) {                                             \
        float a_ = ed_[d_];                                                           \
        ef0_ = fmaf(a_, weR[d_].x, ef0_); ef1_ = fmaf(a_, weR[d_].y, ef1_);           \
        ef2_ = fmaf(a_, weR[d_].z, ef2_); ef3_ = fmaf(a_, weR[d_].w, ef3_);           \
    }                                                                                 \
    float s0_ = xlvS[s].x + xrv.x + ef0_;                                             \
    float s1_ = xlvS[s].y + xrv.y + ef1_;                                             \
    float s2_ = xlvS[s].z + xrv.z + ef2_;                                             \
    float s3_ = xlvS[s].w + xrv.w + ef3_;                                             \
    s0_ = fmaxf(s0_, 0.f) + NEG * fminf(s0_, 0.f);                                    \
    s1_ = fmaxf(s1_, 0.f) + NEG * fminf(s1_, 0.f);                                    \
    s2_ = fmaxf(s2_, 0.f) + NEG * fminf(s2_, 0.f);                                    \
    s3_ = fmaxf(s3_, 0.f) + NEG * fminf(s3_, 0.f);                                    \
    float l_ = fmaf(s0_, attR.x, fmaf(s1_, attR.y, fmaf(s2_, attR.z, s3_ * attR.w))); \
    l_ += __shfl_xor(l_, 1, 64);                                                      \
    l_ += __shfl_xor(l_, 2, 64);                                                      \
    l_ += __shfl_xor(l_, 4, 64);                                                      \
    l_ += __shfl_xor(l_, 8, 64);                                                      \
    if (H == 1) { l_ += __shfl_xor(l_, 16, 64); l_ += __shfl_xor(l_, 32, 64); }       \
    float nm_ = fmaxf(m, l_);                                                         \
    float sc_ = __expf(m - nm_);                                                      \
    float w_  = __expf(l_ - nm_);                                                     \
    z = fmaf(z, sc_, w_);                                                             \
    m = nm_;                                                                          \
    acc.x = fmaf(acc.x, sc_, w_ * xlvS[s].x);                                         \
    acc.y = fmaf(acc.y, sc_, w_ * xlvS[s].y);                                         \
    acc.z = fmaf(acc.z, sc_, w_ * xlvS[s].z);                                         \
    acc.w = fmaf(acc.w, sc_, w_ * xlvS[s].w);                                         \
} while (0)

template <int H, int RELU, int OUTMODE>
__global__ __launch_bounds__(256, 4) void k_gat(
    const float* __restrict__ xl, const float* __restrict__ xr,
    const float* __restrict__ ea, const float* __restrict__ loop_attr,
    const int2* __restrict__ elist2, const int* __restrict__ rowptr,
    const float* __restrict__ We, const float* __restrict__ att,
    const float* __restrict__ bias, float* __restrict__ out,
    unsigned short* __restrict__ outH, unsigned short* __restrict__ outL)
{
    int t = threadIdx.x;
    int lane = t & 63;
    int n = __builtin_amdgcn_readfirstlane(blockIdx.x * 4 + (t >> 6));
    int base = lane * 4;

    float4 weR[ED_DIM];
    #pragma unroll
    for (int d = 0; d < ED_DIM; ++d)
        weR[d] = *(const float4*)(We + d * FEAT + base);

    float4 attR = *(const float4*)(att + base);
    float4 xrv  = *(const float4*)(xr + (size_t)n * FEAT + base);

    float m = -INFINITY, z = 0.f;
    float4 acc = {0.f, 0.f, 0.f, 0.f};

    int p0 = rowptr[n], p1 = rowptr[n + 1];   // p1 > p0 guaranteed (self-loop)
    int pe = p1 - 1;

    int2   eS[2];
    float4 evS[2][4];
    float4 xlvS[2];

    eS[0] = elist2[p0];
    { int pc = p0 + 1 > pe ? pe : p0 + 1; eS[1] = elist2[pc]; }
    XELOAD(0);

    int p = p0;
    while (true) {
        XELOAD(1);
        { int pn = p + 2 > pe ? pe : p + 2; eS[0] = elist2[pn]; }
        COMPUTE(0);
        if (++p >= p1) break;
        XELOAD(0);
        { int pn = p + 2 > pe ? pe : p + 2; eS[1] = elist2[pn]; }
        COMPUTE(1);
        if (++p >= p1) break;
    }

    float inv = 1.0f / (z + 1e-16f);
    float4 bs = *(const float4*)(bias + base);
    float4 o;
    o.x = fmaf(acc.x, inv, bs.x);
    o.y = fmaf(acc.y, inv, bs.y);
    o.z = fmaf(acc.z, inv, bs.z);
    o.w = fmaf(acc.w, inv, bs.w);
    if (RELU) {
        o.x = fmaxf(o.x, 0.f); o.y = fmaxf(o.y, 0.f);
        o.z = fmaxf(o.z, 0.f); o.w = fmaxf(o.w, 0.f);
    }
    if (OUTMODE == 2)
        *(float4*)(out + (size_t)n * FEAT + base) = o;
    ushort4 oh, ol;
    bsplit(o.x, oh.x, ol.x);
    bsplit(o.y, oh.y, ol.y);
    bsplit(o.z, oh.z, ol.z);
    bsplit(o.w, oh.w, ol.w);
    *(ushort4*)(outH + (size_t)n * FEAT + base) = oh;
    *(ushort4*)(outL + (size_t)n * FEAT + base) = ol;
}

// ---------------- gate score: gate[n] = ghid[n,:] @ W2 + b2 ----------------
__global__ __launch_bounds__(256) void k_gate_score(const float* __restrict__ ghid,
    const float* __restrict__ W2, const float* __restrict__ b2, float* __restrict__ gate)
{
    int lane = threadIdx.x & 63;
    int n = blockIdx.x * 4 + (threadIdx.x >> 6);
    float v = ghid[(size_t)n * 128 + lane] * W2[lane] + ghid[(size_t)n * 128 + lane + 64] * W2[lane + 64];
    #pragma unroll
    for (int off = 32; off > 0; off >>= 1) v += __shfl_xor(v, off, 64);
    if (lane == 0) gate[n] = v + b2[0];
}

// ---------------- attentional pooling: one block per batch segment ----------------
__device__ __forceinline__ int lbound(const int* a, int n, int v)
{
    int lo = 0, hi = n;
    while (lo < hi) { int mid = (lo + hi) >> 1; if (a[mid] < v) lo = mid + 1; else hi = mid; }
    return lo;
}

__global__ __launch_bounds__(256) void k_pool(const float* __restrict__ gate,
    const float* __restrict__ h, const int* __restrict__ batch, float* __restrict__ g)
{
    int b = blockIdx.x;
    int t = threadIdx.x;
    __shared__ float red[256];
    int start = lbound(batch, N_NODES, b);
    int end   = lbound(batch, N_NODES, b + 1);

    float mx = -INFINITY;
    for (int n = start + t; n < end; n += 256) mx = fmaxf(mx, gate[n]);
    red[t] = mx; __syncthreads();
    for (int s = 128; s; s >>= 1) { if (t < s) red[t] = fmaxf(red[t], red[t + s]); __syncthreads(); }
    float m = red[0];
    __syncthreads();

    float zs = 0.f;
    for (int n = start + t; n < end; n += 256) zs += __expf(gate[n] - m);
    red[t] = zs; __syncthreads();
    for (int s = 128; s; s >>= 1) { if (t < s) red[t] += red[t + s]; __syncthreads(); }
    float z = red[0];

    float gs = 0.f;
    for (int n = start; n < end; ++n) gs += __expf(gate[n] - m) * h[(size_t)n * FEAT + t];
    g[b * FEAT + t] = gs / (z + 1e-16f);
}

// ---------------- regression head: per-batch tiny MLP ----------------
__global__ __launch_bounds__(128) void k_reg(const float* __restrict__ g,
    const float* __restrict__ W1, const float* __restrict__ b1,
    const float* __restrict__ W2, const float* __restrict__ b2, float* __restrict__ out)
{
    int b = blockIdx.x, t = threadIdx.x;
    __shared__ float sg[FEAT];
    sg[t] = g[b * FEAT + t];
    sg[t + 128] = g[b * FEAT + t + 128];
    __syncthreads();
    float hv = b1[t];
    for (int k = 0; k < FEAT; ++k) hv += sg[k] * W1[k * 128 + t];
    hv = fmaxf(hv, 0.f);
    __shared__ float p0s[128], p1s[128];
    p0s[t] = hv * W2[t * 2 + 0];
    p1s[t] = hv * W2[t * 2 + 1];
    __syncthreads();
    for (int s = 64; s; s >>= 1) {
        if (t < s) { p0s[t] += p0s[t + s]; p1s[t] += p1s[t + s]; }
        __syncthreads();
    }
    if (t == 0) { out[b * 2 + 0] = p0s[0] + b2[0]; out[b * 2 + 1] = p1s[0] + b2[1]; }
}

// ---------------- launch ----------------
extern "C" void kernel_launch(void* const* d_in, const int* in_sizes, int n_in,
                              void* d_out, int out_size, void* d_ws, size_t ws_size,
                              hipStream_t stream)
{
    const float* x       = (const float*)d_in[0];
    const int*   ei      = (const int*)d_in[1];   // [2,E]
    const float* ea      = (const float*)d_in[2];
    const int*   batch   = (const int*)d_in[3];
    const float* c1_Wl   = (const float*)d_in[5];
    const float* c1_bl   = (const float*)d_in[6];
    const float* c1_Wr   = (const float*)d_in[7];
    const float* c1_br   = (const float*)d_in[8];
    const float* c1_We   = (const float*)d_in[9];
    const float* c1_att  = (const float*)d_in[10];
    const float* c1_bias = (const float*)d_in[11];
    const float* c2_Wl   = (const float*)d_in[12];
    const float* c2_bl   = (const float*)d_in[13];
    const float* c2_Wr   = (const float*)d_in[14];
    const float* c2_br   = (const float*)d_in[15];
    const float* c2_We   = (const float*)d_in[16];
    const float* c2_att  = (const float*)d_in[17];
    const float* c2_bias = (const float*)d_in[18];
    const float* c3_Wl   = (const float*)d_in[19];
    const float* c3_bl   = (const float*)d_in[20];
    const float* c3_Wr   = (const float*)d_in[21];
    const float* c3_br   = (const float*)d_in[22];
    const float* c3_We   = (const float*)d_in[23];
    const float* c3_att  = (const float*)d_in[24];
    const float* c3_bias = (const float*)d_in[25];
    const float* gate_W1 = (const float*)d_in[26];
    const float* gate_b1 = (const float*)d_in[27];
    const float* gate_W2 = (const float*)d_in[28];
    const float* gate_b2 = (const float*)d_in[29];
    const float* reg_W1  = (const float*)d_in[30];
    const float* reg_b1  = (const float*)d_in[31];
    const float* reg_W2  = (const float*)d_in[32];
    const float* reg_b2  = (const float*)d_in[33];

    const int* srcArr = ei;            // row 0
    const int* dstArr = ei + N_EDGES;  // row 1

    float* ws = (float*)d_ws;
    size_t off = 0;
    auto alloc = [&](size_t nf) { float* p = ws + off; off += (nf + 63) & ~(size_t)63; return p; };
    float* xl        = alloc((size_t)N_NODES * FEAT);
    float* xr        = alloc((size_t)N_NODES * FEAT);
    float* h         = alloc((size_t)N_NODES * FEAT);
    float* loop_attr = alloc((size_t)N_NODES * ED_DIM);
    float* gpool     = alloc((size_t)BATCH * FEAT);
    unsigned short* Ah = (unsigned short*)alloc((size_t)N_NODES * FEAT / 2);  // bf16 hi
    unsigned short* Al = (unsigned short*)alloc((size_t)N_NODES * FEAT / 2);  // bf16 lo
    unsigned short* wlT_h = (unsigned short*)alloc(FEAT * FEAT / 2);
    unsigned short* wlT_l = (unsigned short*)alloc(FEAT * FEAT / 2);
    unsigned short* wrT_h = (unsigned short*)alloc(FEAT * FEAT / 2);
    unsigned short* wrT_l = (unsigned short*)alloc(FEAT * FEAT / 2);
    int* ibase  = (int*)(ws + off);
    int* deg    = ibase;
    int* fill   = ibase + N_NODES;
    int* rowptr = ibase + 2 * N_NODES;            // N+1 ints
    int* bsum   = ibase + 3 * N_NODES + 64;
    int* boff   = bsum + 256;
    int2* elist2 = (int2*)(boff + 256);           // ETOT int2

    // aliases at disjoint lifetimes
    float* ghid = xl;                       // after L3 gat, xl is dead
    float* gate = xr;

    hipMemsetAsync(deg, 0, (size_t)2 * N_NODES * sizeof(int), stream);

    // CSR build, then self-loop mean attrs from CSR
    k_deg<<<(ETOT + 255) / 256, 256, 0, stream>>>(dstArr, deg);
    k_scan1<<<NCHUNK, 256, 0, stream>>>(deg, bsum);
    k_scan2<<<1, 256, 0, stream>>>(bsum, boff, rowptr);
    k_scan3<<<NCHUNK, 256, 0, stream>>>(deg, boff, rowptr);
    k_fill<<<(ETOT + 255) / 256, 256, 0, stream>>>(srcArr, dstArr, rowptr, fill, elist2);
    k_loop_csr<<<(N_NODES * ED_DIM + 255) / 256, 256, 0, stream>>>(elist2, rowptr, ea, loop_attr);

    // layer 1 (in: x [N,128], K=128)
    {
        int n4 = N_NODES * IN_DIM / 4;
        k_cvt<<<(n4 + 255) / 256, 256, 0, stream>>>(x, Ah, Al, n4);
        k_cvtT<<<(IN_DIM * FEAT + 255) / 256, 256, 0, stream>>>(c1_Wl, wlT_h, wlT_l, IN_DIM, FEAT);
        k_cvtT<<<(IN_DIM * FEAT + 255) / 256, 256, 0, stream>>>(c1_Wr, wrT_h, wrT_l, IN_DIM, FEAT);
        launch_mgemm(Ah, Al, wlT_h, wlT_l, c1_bl, xl, N_NODES, FEAT, IN_DIM, 0, stream);
        launch_mgemm(Ah, Al, wrT_h, wrT_l, c1_br, xr, N_NODES, FEAT, IN_DIM, 0, stream);
    }
    k_gat<4, 1, 1><<<N_NODES / 4, 256, 0, stream>>>(xl, xr, ea, loop_attr, elist2, rowptr,
                                                    c1_We, c1_att, c1_bias, h, Ah, Al);
    // layer 2 (K=256); input Ah/Al written by L1 k_gat
    {
        k_cvtT<<<(FEAT * FEAT + 255) / 256, 256, 0, stream>>>(c2_Wl, wlT_h, wlT_l, FEAT, FEAT);
        k_cvtT<<<(FEAT * FEAT + 255) / 256, 256, 0, stream>>>(c2_Wr, wrT_h, wrT_l, FEAT, FEAT);
        launch_mgemm(Ah, Al, wlT_h, wlT_l, c2_bl, xl, N_NODES, FEAT, FEAT, 0, stream);
        launch_mgemm(Ah, Al, wrT_h, wrT_l, c2_br, xr, N_NODES, FEAT, FEAT, 0, stream);
    }
    k_gat<4, 1, 1><<<N_NODES / 4, 256, 0, stream>>>(xl, xr, ea, loop_attr, elist2, rowptr,
                                                    c2_We, c2_att, c2_bias, h, Ah, Al);
    // layer 3 (heads=1, no relu); writes h (for pooling) + split (for gate GEMM)
    {
        k_cvtT<<<(FEAT * FEAT + 255) / 256, 256, 0, stream>>>(c3_Wl, wlT_h, wlT_l, FEAT, FEAT);
        k_cvtT<<<(FEAT * FEAT + 255) / 256, 256, 0, stream>>>(c3_Wr, wrT_h, wrT_l, FEAT, FEAT);
        launch_mgemm(Ah, Al, wlT_h, wlT_l, c3_bl, xl, N_NODES, FEAT, FEAT, 0, stream);
        launch_mgemm(Ah, Al, wrT_h, wrT_l, c3_br, xr, N_NODES, FEAT, FEAT, 0, stream);
    }
    k_gat<1, 0, 2><<<N_NODES / 4, 256, 0, stream>>>(xl, xr, ea, loop_attr, elist2, rowptr,
                                                    c3_We, c3_att, c3_bias, h, Ah, Al);

    // pooling + head (gate hidden GEMM: K=256, N=128, relu)
    {
        k_cvtT<<<(FEAT * 128 + 255) / 256, 256, 0, stream>>>(gate_W1, wlT_h, wlT_l, FEAT, 128);
        launch_mgemm(Ah, Al, wlT_h, wlT_l, gate_b1, ghid, N_NODES, 128, FEAT, 1, stream);
    }
    k_gate_score<<<N_NODES / 4, 256, 0, stream>>>(ghid, gate_W2, gate_b2, gate);
    k_pool<<<BATCH, 256, 0, stream>>>(gate, h, batch, gpool);
    k_reg<<<BATCH, 128, 0, stream>>>(gpool, reg_W1, reg_b1, reg_W2, reg_b2, (float*)d_out);
}

// Round 11
// 1037.093 us; speedup vs baseline: 1.1925x; 1.1925x over previous
//
#include <hip/hip_runtime.h>
#include <math.h>

constexpr int N_NODES = 40000;
constexpr int N_EDGES = 500000;
constexpr int ETOT    = N_EDGES + N_NODES;
constexpr int IN_DIM  = 128;
constexpr int ED_DIM  = 16;
constexpr int FEAT    = 256;   // H*C for every layer
constexpr int BATCH   = 128;
constexpr float NEG   = 0.2f;
constexpr int NCHUNK  = (N_NODES + 255) / 256;  // 157

typedef __bf16 bf16x8 __attribute__((ext_vector_type(8)));
typedef float  f32x4  __attribute__((ext_vector_type(4)));

// ---------------- CSR build (by dst, incl. self loops) ----------------
__global__ __launch_bounds__(256) void k_deg(const int* __restrict__ dst, int* __restrict__ deg)
{
    int e = blockIdx.x * 256 + threadIdx.x;
    if (e >= ETOT) return;
    int v = e < N_EDGES ? dst[e] : e - N_EDGES;
    atomicAdd(&deg[v], 1);
}

__global__ __launch_bounds__(256) void k_scan1(const int* __restrict__ deg, int* __restrict__ bsum)
{
    __shared__ int s[256];
    int t = threadIdx.x;
    int idx = blockIdx.x * 256 + t;
    s[t] = idx < N_NODES ? deg[idx] : 0;
    __syncthreads();
    for (int st = 128; st; st >>= 1) { if (t < st) s[t] += s[t + st]; __syncthreads(); }
    if (t == 0) bsum[blockIdx.x] = s[0];
}

__global__ __launch_bounds__(256) void k_scan2(const int* __restrict__ bsum,
    int* __restrict__ boff, int* __restrict__ rowptr)
{
    __shared__ int s[256];
    int t = threadIdx.x;
    int v = t < NCHUNK ? bsum[t] : 0;
    s[t] = v;
    __syncthreads();
    for (int off = 1; off < 256; off <<= 1) {
        int x = (t >= off) ? s[t - off] : 0;
        __syncthreads();
        s[t] += x;
        __syncthreads();
    }
    if (t < NCHUNK) boff[t] = s[t] - v;
    if (t == 0) rowptr[N_NODES] = ETOT;
}

__global__ __launch_bounds__(256) void k_scan3(const int* __restrict__ deg,
    const int* __restrict__ boff, int* __restrict__ rowptr)
{
    __shared__ int s[256];
    int t = threadIdx.x;
    int idx = blockIdx.x * 256 + t;
    int v = idx < N_NODES ? deg[idx] : 0;
    s[t] = v;
    __syncthreads();
    for (int off = 1; off < 256; off <<= 1) {
        int x = (t >= off) ? s[t - off] : 0;
        __syncthreads();
        s[t] += x;
        __syncthreads();
    }
    if (idx < N_NODES) rowptr[idx] = boff[blockIdx.x] + s[t] - v;
}

// elist2[pos] = (src, eid)
__global__ __launch_bounds__(256) void k_fill(const int* __restrict__ srcA, const int* __restrict__ dst,
    const int* __restrict__ rowptr, int* __restrict__ fill, int2* __restrict__ elist2)
{
    int e = blockIdx.x * 256 + threadIdx.x;
    if (e >= ETOT) return;
    int v = e < N_EDGES ? dst[e]  : e - N_EDGES;
    int s = e < N_EDGES ? srcA[e] : e - N_EDGES;
    int pos = rowptr[v] + atomicAdd(&fill[v], 1);
    elist2[pos] = make_int2(s, e);
}

// ---------------- self-loop mean edge attr via CSR (no atomics) ----------------
__global__ __launch_bounds__(256) void k_loop_csr(const int2* __restrict__ elist2,
    const int* __restrict__ rowptr, const float* __restrict__ ea, float* __restrict__ loop_attr)
{
    int t = blockIdx.x * 256 + threadIdx.x;
    if (t >= N_NODES * ED_DIM) return;
    int n = t >> 4, d = t & 15;
    int p0 = rowptr[n], p1 = rowptr[n + 1];
    float s = 0.f; int c = 0;
    for (int p = p0; p < p1; ++p) {
        int e = elist2[p].y;
        if (e < N_EDGES) { s += ea[(size_t)e * ED_DIM + d]; ++c; }
    }
    loop_attr[t] = s / (float)(c > 0 ? c : 1);
}

// ---------------- split fp32 -> bf16 hi/lo ----------------
__device__ __forceinline__ void bsplit(float x, unsigned short& h, unsigned short& l)
{
    unsigned u = __float_as_uint(x);
    unsigned r = (u + 0x7FFFu + ((u >> 16) & 1u)) >> 16;
    h = (unsigned short)r;
    float rem = x - __uint_as_float(r << 16);
    unsigned u2 = __float_as_uint(rem);
    l = (unsigned short)((u2 + 0x7FFFu + ((u2 >> 16) & 1u)) >> 16);
}

__global__ __launch_bounds__(256) void k_cvt(const float* __restrict__ X,
    unsigned short* __restrict__ Xh, unsigned short* __restrict__ Xl, int n4)
{
    int i = blockIdx.x * 256 + threadIdx.x;
    if (i >= n4) return;
    float4 v = ((const float4*)X)[i];
    ushort4 h, l;
    bsplit(v.x, h.x, l.x);
    bsplit(v.y, h.y, l.y);
    bsplit(v.z, h.z, l.z);
    bsplit(v.w, h.w, l.w);
    ((ushort4*)Xh)[i] = h;
    ((ushort4*)Xl)[i] = l;
}

// W[K][N] fp32 -> WhT/WlT [N][K] bf16 (transposed for B-fragment b128 reads)
__global__ __launch_bounds__(256) void k_cvtT(const float* __restrict__ W,
    unsigned short* __restrict__ WhT, unsigned short* __restrict__ WlT, int K, int N)
{
    int i = blockIdx.x * 256 + threadIdx.x;
    if (i >= K * N) return;
    int k = i / N, n = i - k * N;
    unsigned short h, l;
    bsplit(W[i], h, l);
    WhT[(size_t)n * K + k] = h;
    WlT[(size_t)n * K + k] = l;
}

// ---------------- split-bf16 MFMA GEMM, global_load_lds staging ----------------
// C = Ah·Bh + Ah·Bl + Al·Bh + bias (+relu). 128x128 block, 4 waves, wave = 64x64.
// LDS fragment-major: slot s = tile*64 + lane (16 B) -> staging and frag reads are
// both conflict-free b128. Staging via DMA (no VGPR round-trip).
// A frag: lane holds A[m=lane&15][k=(lane>>4)*8+j]; B frag: B^T mirrored;
// D: col=lane&15, row=(lane>>4)*4+i  (HW-verified in round 9).

__device__ __forceinline__ void stage16(const unsigned short* g, void* lds)
{
#if __has_builtin(__builtin_amdgcn_global_load_lds)
    __builtin_amdgcn_global_load_lds(
        (const __attribute__((address_space(1))) void*)g,
        (__attribute__((address_space(3))) void*)lds, 16, 0, 0);
#else
    ((uint4*)lds)[threadIdx.x & 63] = *(const uint4*)g;
#endif
}

__global__ __launch_bounds__(256) void k_mgemm(
    const unsigned short* __restrict__ Ah, const unsigned short* __restrict__ Al,
    const unsigned short* __restrict__ BhT, const unsigned short* __restrict__ BlT,
    const float* __restrict__ bias, float* __restrict__ C,
    int M, int N, int K, int act)
{
    __shared__ uint4 sAh[512], sAl[512], sBh[512], sBl[512];   // 8 KB each, 32 KB total

    int t = threadIdx.x;
    int lane = t & 63;
    int w = t >> 6;
    int mh = w >> 1, nh = w & 1;
    int bm = blockIdx.x * 128, bn = blockIdx.y * 128;
    int q = lane >> 4, lm = lane & 15;

    // staging: wave w stages tiles {w, w+4} of each array.
    int ar0 = bm + w * 16 + lm;        ar0 = ar0 < M ? ar0 : M - 1;
    int ar1 = bm + (w + 4) * 16 + lm;  ar1 = ar1 < M ? ar1 : M - 1;
    int bc0 = bn + w * 16 + lm;
    int bc1 = bn + (w + 4) * 16 + lm;
    size_t aoff0 = (size_t)ar0 * K + q * 8;
    size_t aoff1 = (size_t)ar1 * K + q * 8;
    size_t boff0 = (size_t)bc0 * K + q * 8;
    size_t boff1 = (size_t)bc1 * K + q * 8;

    f32x4 acc[4][4] = {};

    int nk = K >> 5;
    for (int ks = 0; ks < nk; ++ks) {
        int k0 = ks << 5;
        if (ks) __syncthreads();              // protect LDS before overwrite
        stage16(Ah  + aoff0 + k0, &sAh[w * 64]);
        stage16(Ah  + aoff1 + k0, &sAh[(w + 4) * 64]);
        stage16(Al  + aoff0 + k0, &sAl[w * 64]);
        stage16(Al  + aoff1 + k0, &sAl[(w + 4) * 64]);
        stage16(BhT + boff0 + k0, &sBh[w * 64]);
        stage16(BhT + boff1 + k0, &sBh[(w + 4) * 64]);
        stage16(BlT + boff0 + k0, &sBl[w * 64]);
        stage16(BlT + boff1 + k0, &sBl[(w + 4) * 64]);
        __syncthreads();                      // drains vmcnt -> staging complete

        bf16x8 fah[4], fal[4], fbh[4], fbl[4];
        #pragma unroll
        for (int mt = 0; mt < 4; ++mt) {
            fah[mt] = __builtin_bit_cast(bf16x8, sAh[(mh * 4 + mt) * 64 + lane]);
            fal[mt] = __builtin_bit_cast(bf16x8, sAl[(mh * 4 + mt) * 64 + lane]);
        }
        #pragma unroll
        for (int nt = 0; nt < 4; ++nt) {
            fbh[nt] = __builtin_bit_cast(bf16x8, sBh[(nh * 4 + nt) * 64 + lane]);
            fbl[nt] = __builtin_bit_cast(bf16x8, sBl[(nh * 4 + nt) * 64 + lane]);
        }
        #pragma unroll
        for (int mt = 0; mt < 4; ++mt)
            #pragma unroll
            for (int nt = 0; nt < 4; ++nt) {
                acc[mt][nt] = __builtin_amdgcn_mfma_f32_16x16x32_bf16(fah[mt], fbh[nt], acc[mt][nt], 0, 0, 0);
                acc[mt][nt] = __builtin_amdgcn_mfma_f32_16x16x32_bf16(fah[mt], fbl[nt], acc[mt][nt], 0, 0, 0);
                acc[mt][nt] = __builtin_amdgcn_mfma_f32_16x16x32_bf16(fal[mt], fbh[nt], acc[mt][nt], 0, 0, 0);
            }
    }

    #pragma unroll
    for (int nt = 0; nt < 4; ++nt) {
        int col = bn + nh * 64 + nt * 16 + lm;
        float bb = bias[col];
        #pragma unroll
        for (int mt = 0; mt < 4; ++mt) {
            #pragma unroll
            for (int i = 0; i < 4; ++i) {
                int row = bm + mh * 64 + mt * 16 + q * 4 + i;
                if (row < M) {
                    float o = acc[mt][nt][i] + bb;
                    if (act) o = fmaxf(o, 0.f);
                    C[(size_t)row * N + col] = o;
                }
            }
        }
    }
}

static void launch_mgemm(const unsigned short* Ah, const unsigned short* Al,
                         const unsigned short* BhT, const unsigned short* BlT,
                         const float* bias, float* C, int M, int N, int K, int act,
                         hipStream_t stream)
{
    dim3 grid((M + 127) / 128, N / 128);
    k_mgemm<<<grid, 256, 0, stream>>>(Ah, Al, BhT, BlT, bias, C, M, N, K, act);
}

// ---------------- fused GATv2 with fused split-precision output ----------------
// OUTMODE: 1 = write bf16 hi/lo only; 2 = write fp32 h AND bf16 hi/lo.
#define XELOAD(s) do {                                                                \
    int src_ = __builtin_amdgcn_readfirstlane(eS[s].x);                               \
    int e_   = __builtin_amdgcn_readfirstlane(eS[s].y);                               \
    const float4* eb4_ = reinterpret_cast<const float4*>(                             \
        (e_ < N_EDGES) ? ea + (size_t)e_ * ED_DIM                                     \
                       : loop_attr + (size_t)src_ * ED_DIM);                          \
    evS[s][0] = eb4_[0]; evS[s][1] = eb4_[1];                                         \
    evS[s][2] = eb4_[2]; evS[s][3] = eb4_[3];                                         \
    xlvS[s] = *(const float4*)(xl + (size_t)src_ * FEAT + base);                      \
} while (0)

#define COMPUTE(s) do {                                                               \
    float ef0_ = 0.f, ef1_ = 0.f, ef2_ = 0.f, ef3_ = 0.f;                             \
    const float* ed_ = (const float*)evS[s];                                          \
    _Pragma("unroll")                                                                 \
    for (int d_ = 0; d_ < ED_DIM; ++d_) {                                             \
        float a_ = ed_[d_];                                                           \
        ef0_ = fmaf(a_, weR[d_].x, ef0_); ef1_ = fmaf(a_, weR[d_].y, ef1_);           \
        ef2_ = fmaf(a_, weR[d_].z, ef2_); ef3_ = fmaf(a_, weR[d_].w, ef3_);           \
    }                                                                                 \
    float s0_ = xlvS[s].x + xrv.x + ef0_;                                             \
    float s1_ = xlvS[s].y + xrv.y + ef1_;                                             \
    float s2_ = xlvS[s].z + xrv.z + ef2_;                                             \
    float s3_ = xlvS[s].w + xrv.w + ef3_;                                             \
    s0_ = fmaxf(s0_, 0.f) + NEG * fminf(s0_, 0.f);                                    \
    s1_ = fmaxf(s1_, 0.f) + NEG * fminf(s1_, 0.f);                                    \
    s2_ = fmaxf(s2_, 0.f) + NEG * fminf(s2_, 0.f);                                    \
    s3_ = fmaxf(s3_, 0.f) + NEG * fminf(s3_, 0.f);                                    \
    float l_ = fmaf(s0_, attR.x, fmaf(s1_, attR.y, fmaf(s2_, attR.z, s3_ * attR.w))); \
    l_ += __shfl_xor(l_, 1, 64);                                                      \
    l_ += __shfl_xor(l_, 2, 64);                                                      \
    l_ += __shfl_xor(l_, 4, 64);                                                      \
    l_ += __shfl_xor(l_, 8, 64);                                                      \
    if (H == 1) { l_ += __shfl_xor(l_, 16, 64); l_ += __shfl_xor(l_, 32, 64); }       \
    float nm_ = fmaxf(m, l_);                                                         \
    float sc_ = __expf(m - nm_);                                                      \
    float w_  = __expf(l_ - nm_);                                                     \
    z = fmaf(z, sc_, w_);                                                             \
    m = nm_;                                                                          \
    acc.x = fmaf(acc.x, sc_, w_ * xlvS[s].x);                                         \
    acc.y = fmaf(acc.y, sc_, w_ * xlvS[s].y);                                         \
    acc.z = fmaf(acc.z, sc_, w_ * xlvS[s].z);                                         \
    acc.w = fmaf(acc.w, sc_, w_ * xlvS[s].w);                                         \
} while (0)

template <int H, int RELU, int OUTMODE>
__global__ __launch_bounds__(256, 4) void k_gat(
    const float* __restrict__ xl, const float* __restrict__ xr,
    const float* __restrict__ ea, const float* __restrict__ loop_attr,
    const int2* __restrict__ elist2, const int* __restrict__ rowptr,
    const float* __restrict__ We, const float* __restrict__ att,
    const float* __restrict__ bias, float* __restrict__ out,
    unsigned short* __restrict__ outH, unsigned short* __restrict__ outL)
{
    int t = threadIdx.x;
    int lane = t & 63;
    int n = __builtin_amdgcn_readfirstlane(blockIdx.x * 4 + (t >> 6));
    int base = lane * 4;

    float4 weR[ED_DIM];
    #pragma unroll
    for (int d = 0; d < ED_DIM; ++d)
        weR[d] = *(const float4*)(We + d * FEAT + base);

    float4 attR = *(const float4*)(att + base);
    float4 xrv  = *(const float4*)(xr + (size_t)n * FEAT + base);

    float m = -INFINITY, z = 0.f;
    float4 acc = {0.f, 0.f, 0.f, 0.f};

    int p0 = rowptr[n], p1 = rowptr[n + 1];   // p1 > p0 guaranteed (self-loop)
    int pe = p1 - 1;

    int2   eS[2];
    float4 evS[2][4];
    float4 xlvS[2];

    eS[0] = elist2[p0];
    { int pc = p0 + 1 > pe ? pe : p0 + 1; eS[1] = elist2[pc]; }
    XELOAD(0);

    int p = p0;
    while (true) {
        XELOAD(1);
        { int pn = p + 2 > pe ? pe : p + 2; eS[0] = elist2[pn]; }
        COMPUTE(0);
        if (++p >= p1) break;
        XELOAD(0);
        { int pn = p + 2 > pe ? pe : p + 2; eS[1] = elist2[pn]; }
        COMPUTE(1);
        if (++p >= p1) break;
    }

    float inv = 1.0f / (z + 1e-16f);
    float4 bs = *(const float4*)(bias + base);
    float4 o;
    o.x = fmaf(acc.x, inv, bs.x);
    o.y = fmaf(acc.y, inv, bs.y);
    o.z = fmaf(acc.z, inv, bs.z);
    o.w = fmaf(acc.w, inv, bs.w);
    if (RELU) {
        o.x = fmaxf(o.x, 0.f); o.y = fmaxf(o.y, 0.f);
        o.z = fmaxf(o.z, 0.f); o.w = fmaxf(o.w, 0.f);
    }
    if (OUTMODE == 2)
        *(float4*)(out + (size_t)n * FEAT + base) = o;
    ushort4 oh, ol;
    bsplit(o.x, oh.x, ol.x);
    bsplit(o.y, oh.y, ol.y);
    bsplit(o.z, oh.z, ol.z);
    bsplit(o.w, oh.w, ol.w);
    *(ushort4*)(outH + (size_t)n * FEAT + base) = oh;
    *(ushort4*)(outL + (size_t)n * FEAT + base) = ol;
}

// ---------------- gate score: gate[n] = ghid[n,:] @ W2 + b2 ----------------
__global__ __launch_bounds__(256) void k_gate_score(const float* __restrict__ ghid,
    const float* __restrict__ W2, const float* __restrict__ b2, float* __restrict__ gate)
{
    int lane = threadIdx.x & 63;
    int n = blockIdx.x * 4 + (threadIdx.x >> 6);
    float v = ghid[(size_t)n * 128 + lane] * W2[lane] + ghid[(size_t)n * 128 + lane + 64] * W2[lane + 64];
    #pragma unroll
    for (int off = 32; off > 0; off >>= 1) v += __shfl_xor(v, off, 64);
    if (lane == 0) gate[n] = v + b2[0];
}

// ---------------- attentional pooling: one block per batch segment ----------------
__device__ __forceinline__ int lbound(const int* a, int n, int v)
{
    int lo = 0, hi = n;
    while (lo < hi) { int mid = (lo + hi) >> 1; if (a[mid] < v) lo = mid + 1; else hi = mid; }
    return lo;
}

__global__ __launch_bounds__(256) void k_pool(const float* __restrict__ gate,
    const float* __restrict__ h, const int* __restrict__ batch, float* __restrict__ g)
{
    int b = blockIdx.x;
    int t = threadIdx.x;
    __shared__ float red[256];
    int start = lbound(batch, N_NODES, b);
    int end   = lbound(batch, N_NODES, b + 1);

    float mx = -INFINITY;
    for (int n = start + t; n < end; n += 256) mx = fmaxf(mx, gate[n]);
    red[t] = mx; __syncthreads();
    for (int s = 128; s; s >>= 1) { if (t < s) red[t] = fmaxf(red[t], red[t + s]); __syncthreads(); }
    float m = red[0];
    __syncthreads();

    float zs = 0.f;
    for (int n = start + t; n < end; n += 256) zs += __expf(gate[n] - m);
    red[t] = zs; __syncthreads();
    for (int s = 128; s; s >>= 1) { if (t < s) red[t] += red[t + s]; __syncthreads(); }
    float z = red[0];

    float gs = 0.f;
    for (int n = start; n < end; ++n) gs += __expf(gate[n] - m) * h[(size_t)n * FEAT + t];
    g[b * FEAT + t] = gs / (z + 1e-16f);
}

// ---------------- regression head: per-batch tiny MLP ----------------
__global__ __launch_bounds__(128) void k_reg(const float* __restrict__ g,
    const float* __restrict__ W1, const float* __restrict__ b1,
    const float* __restrict__ W2, const float* __restrict__ b2, float* __restrict__ out)
{
    int b = blockIdx.x, t = threadIdx.x;
    __shared__ float sg[FEAT];
    sg[t] = g[b * FEAT + t];
    sg[t + 128] = g[b * FEAT + t + 128];
    __syncthreads();
    float hv = b1[t];
    for (int k = 0; k < FEAT; ++k) hv += sg[k] * W1[k * 128 + t];
    hv = fmaxf(hv, 0.f);
    __shared__ float p0s[128], p1s[128];
    p0s[t] = hv * W2[t * 2 + 0];
    p1s[t] = hv * W2[t * 2 + 1];
    __syncthreads();
    for (int s = 64; s; s >>= 1) {
        if (t < s) { p0s[t] += p0s[t + s]; p1s[t] += p1s[t + s]; }
        __syncthreads();
    }
    if (t == 0) { out[b * 2 + 0] = p0s[0] + b2[0]; out[b * 2 + 1] = p1s[0] + b2[1]; }
}

// ---------------- launch ----------------
extern "C" void kernel_launch(void* const* d_in, const int* in_sizes, int n_in,
                              void* d_out, int out_size, void* d_ws, size_t ws_size,
                              hipStream_t stream)
{
    const float* x       = (const float*)d_in[0];
    const int*   ei      = (const int*)d_in[1];   // [2,E]
    const float* ea      = (const float*)d_in[2];
    const int*   batch   = (const int*)d_in[3];
    const float* c1_Wl   = (const float*)d_in[5];
    const float* c1_bl   = (const float*)d_in[6];
    const float* c1_Wr   = (const float*)d_in[7];
    const float* c1_br   = (const float*)d_in[8];
    const float* c1_We   = (const float*)d_in[9];
    const float* c1_att  = (const float*)d_in[10];
    const float* c1_bias = (const float*)d_in[11];
    const float* c2_Wl   = (const float*)d_in[12];
    const float* c2_bl   = (const float*)d_in[13];
    const float* c2_Wr   = (const float*)d_in[14];
    const float* c2_br   = (const float*)d_in[15];
    const float* c2_We   = (const float*)d_in[16];
    const float* c2_att  = (const float*)d_in[17];
    const float* c2_bias = (const float*)d_in[18];
    const float* c3_Wl   = (const float*)d_in[19];
    const float* c3_bl   = (const float*)d_in[20];
    const float* c3_Wr   = (const float*)d_in[21];
    const float* c3_br   = (const float*)d_in[22];
    const float* c3_We   = (const float*)d_in[23];
    const float* c3_att  = (const float*)d_in[24];
    const float* c3_bias = (const float*)d_in[25];
    const float* gate_W1 = (const float*)d_in[26];
    const float* gate_b1 = (const float*)d_in[27];
    const float* gate_W2 = (const float*)d_in[28];
    const float* gate_b2 = (const float*)d_in[29];
    const float* reg_W1  = (const float*)d_in[30];
    const float* reg_b1  = (const float*)d_in[31];
    const float* reg_W2  = (const float*)d_in[32];
    const float* reg_b2  = (const float*)d_in[33];

    const int* srcArr = ei;            // row 0
    const int* dstArr = ei + N_EDGES;  // row 1

    float* ws = (float*)d_ws;
    size_t off = 0;
    auto alloc = [&](size_t nf) { float* p = ws + off; off += (nf + 63) & ~(size_t)63; return p; };
    float* xl        = alloc((size_t)N_NODES * FEAT);
    float* xr        = alloc((size_t)N_NODES * FEAT);
    float* h         = alloc((size_t)N_NODES * FEAT);
    float* loop_attr = alloc((size_t)N_NODES * ED_DIM);
    float* gpool     = alloc((size_t)BATCH * FEAT);
    unsigned short* Ah = (unsigned short*)alloc((size_t)N_NODES * FEAT / 2);  // bf16 hi
    unsigned short* Al = (unsigned short*)alloc((size_t)N_NODES * FEAT / 2);  // bf16 lo
    unsigned short* wlT_h = (unsigned short*)alloc(FEAT * FEAT / 2);
    unsigned short* wlT_l = (unsigned short*)alloc(FEAT * FEAT / 2);
    unsigned short* wrT_h = (unsigned short*)alloc(FEAT * FEAT / 2);
    unsigned short* wrT_l = (unsigned short*)alloc(FEAT * FEAT / 2);
    int* ibase  = (int*)(ws + off);
    int* deg    = ibase;
    int* fill   = ibase + N_NODES;
    int* rowptr = ibase + 2 * N_NODES;            // N+1 ints
    int* bsum   = ibase + 3 * N_NODES + 64;
    int* boff   = bsum + 256;
    int2* elist2 = (int2*)(boff + 256);           // ETOT int2

    // aliases at disjoint lifetimes
    float* ghid = xl;                       // after L3 gat, xl is dead
    float* gate = xr;

    hipMemsetAsync(deg, 0, (size_t)2 * N_NODES * sizeof(int), stream);

    // CSR build, then self-loop mean attrs from CSR
    k_deg<<<(ETOT + 255) / 256, 256, 0, stream>>>(dstArr, deg);
    k_scan1<<<NCHUNK, 256, 0, stream>>>(deg, bsum);
    k_scan2<<<1, 256, 0, stream>>>(bsum, boff, rowptr);
    k_scan3<<<NCHUNK, 256, 0, stream>>>(deg, boff, rowptr);
    k_fill<<<(ETOT + 255) / 256, 256, 0, stream>>>(srcArr, dstArr, rowptr, fill, elist2);
    k_loop_csr<<<(N_NODES * ED_DIM + 255) / 256, 256, 0, stream>>>(elist2, rowptr, ea, loop_attr);

    // layer 1 (in: x [N,128], K=128)
    {
        int n4 = N_NODES * IN_DIM / 4;
        k_cvt<<<(n4 + 255) / 256, 256, 0, stream>>>(x, Ah, Al, n4);
        k_cvtT<<<(IN_DIM * FEAT + 255) / 256, 256, 0, stream>>>(c1_Wl, wlT_h, wlT_l, IN_DIM, FEAT);
        k_cvtT<<<(IN_DIM * FEAT + 255) / 256, 256, 0, stream>>>(c1_Wr, wrT_h, wrT_l, IN_DIM, FEAT);
        launch_mgemm(Ah, Al, wlT_h, wlT_l, c1_bl, xl, N_NODES, FEAT, IN_DIM, 0, stream);
        launch_mgemm(Ah, Al, wrT_h, wrT_l, c1_br, xr, N_NODES, FEAT, IN_DIM, 0, stream);
    }
    k_gat<4, 1, 1><<<N_NODES / 4, 256, 0, stream>>>(xl, xr, ea, loop_attr, elist2, rowptr,
                                                    c1_We, c1_att, c1_bias, h, Ah, Al);
    // layer 2 (K=256); input Ah/Al written by L1 k_gat
    {
        k_cvtT<<<(FEAT * FEAT + 255) / 256, 256, 0, stream>>>(c2_Wl, wlT_h, wlT_l, FEAT, FEAT);
        k_cvtT<<<(FEAT * FEAT + 255) / 256, 256, 0, stream>>>(c2_Wr, wrT_h, wrT_l, FEAT, FEAT);
        launch_mgemm(Ah, Al, wlT_h, wlT_l, c2_bl, xl, N_NODES, FEAT, FEAT, 0, stream);
        launch_mgemm(Ah, Al, wrT_h, wrT_l, c2_br, xr, N_NODES, FEAT, FEAT, 0, stream);
    }
    k_gat<4, 1, 1><<<N_NODES / 4, 256, 0, stream>>>(xl, xr, ea, loop_attr, elist2, rowptr,
                                                    c2_We, c2_att, c2_bias, h, Ah, Al);
    // layer 3 (heads=1, no relu); writes h (for pooling) + split (for gate GEMM)
    {
        k_cvtT<<<(FEAT * FEAT + 255) / 256, 256, 0, stream>>>(c3_Wl, wlT_h, wlT_l, FEAT, FEAT);
        k_cvtT<<<(FEAT * FEAT + 255) / 256, 256, 0, stream>>>(c3_Wr, wrT_h, wrT_l, FEAT, FEAT);
        launch_mgemm(Ah, Al, wlT_h, wlT_l, c3_bl, xl, N_NODES, FEAT, FEAT, 0, stream);
        launch_mgemm(Ah, Al, wrT_h, wrT_l, c3_br, xr, N_NODES, FEAT, FEAT, 0, stream);
    }
    k_gat<1, 0, 2><<<N_NODES / 4, 256, 0, stream>>>(xl, xr, ea, loop_attr, elist2, rowptr,
                                                    c3_We, c3_att, c3_bias, h, Ah, Al);

    // pooling + head (gate hidden GEMM: K=256, N=128, relu)
    {
        k_cvtT<<<(FEAT * 128 + 255) / 256, 256, 0, stream>>>(gate_W1, wlT_h, wlT_l, FEAT, 128);
        launch_mgemm(Ah, Al, wlT_h, wlT_l, gate_b1, ghid, N_NODES, 128, FEAT, 1, stream);
    }
    k_gate_score<<<N_NODES / 4, 256, 0, stream>>>(ghid, gate_W2, gate_b2, gate);
    k_pool<<<BATCH, 256, 0, stream>>>(gate, h, batch, gpool);
    k_reg<<<BATCH, 128, 0, stream>>>(gpool, reg_W1, reg_b1, reg_W2, reg_b2, (float*)d_out);
}